// Round 10
// baseline (178.657 us; speedup 1.0000x reference)
//
#include <hip/hip_runtime.h>
#include <hip/hip_fp16.h>
#include <cstdint>

#define NPTS 2048
#define NB 8
// float32 of (0.45*0.45 computed in float64) -- matches jnp/np scalar cast.
// NOTE: 0.45f*0.45f is 1 ulp LOWER; do not use it.
#define R2C 0.2025f

__device__ __forceinline__ float fmul(float a, float b) { return __fmul_rn(a, b); }
__device__ __forceinline__ float fadd(float a, float b) { return __fadd_rn(a, b); }

// packed fp16 max (header lacks __hmax2 on gfx950; ISA has v_pk_max_f16)
__device__ __forceinline__ uint hmax2u(uint a, uint b) {
    uint r;
    asm volatile("v_pk_max_f16 %0, %1, %2" : "=v"(r) : "v"(a), "v"(b));
    return r;
}
__device__ __forceinline__ float lo_f(uint u) {
    __half h = __ushort_as_half((unsigned short)(u & 0xffff));
    return __half2float(h);
}
__device__ __forceinline__ float hi_f(uint u) {
    __half h = __ushort_as_half((unsigned short)(u >> 16));
    return __half2float(h);
}

// ---------------- K1: per-point features (unchanged from R8) ----------------
__global__ __launch_bounds__(512, 4) void k_features(
    const float* __restrict__ X,
    const float* __restrict__ W1a, const float* __restrict__ b1a,
    const float* __restrict__ W2a, const float* __restrict__ b2a,
    const float* __restrict__ W1b, const float* __restrict__ b1b,
    const float* __restrict__ W2b, const float* __restrict__ b2b,
    const float* __restrict__ Wc1, const float* __restrict__ bc1,
    __half* __restrict__ fa, __half* __restrict__ fb, float* __restrict__ v)
{
    __shared__ float fat[64 * 33];
    __shared__ float fbt[64 * 67];
    int tid = threadIdx.x;
    int q = __builtin_amdgcn_readfirstlane(tid >> 6);   // wave 0..7 (SGPR)
    int lane = tid & 63;
    int pbase = blockIdx.x * 64;
    int p = pbase + lane;
    int b = p >> 11, i = p & 2047;

    float x0 = X[p * 3 + 0], x1 = X[p * 3 + 1], x2 = X[p * 3 + 2];

    float h[64];
#pragma unroll
    for (int o = 0; o < 32; ++o)
        h[o] = fmaxf(0.f, x0 * W1a[o * 3] + x1 * W1a[o * 3 + 1] + x2 * W1a[o * 3 + 2] + b1a[o]);
#pragma unroll
    for (int oo = 0; oo < 8; oo += 2) {
        int o = q * 8 + oo;
        float a0 = b2a[o], a1 = b2a[o + 1];
#pragma unroll
        for (int k = 0; k < 32; ++k) {
            a0 = fmaf(h[k], W2a[o * 32 + k], a0);
            a1 = fmaf(h[k], W2a[(o + 1) * 32 + k], a1);
        }
        __half2 hh = __floats2half2_rn(fmaxf(0.f, a0), fmaxf(0.f, a1));
        fat[lane * 33 + q * 4 + (oo >> 1)] = *(float*)&hh;
    }
#pragma unroll
    for (int o = 0; o < 64; ++o)
        h[o] = fmaxf(0.f, x0 * W1b[o * 3] + x1 * W1b[o * 3 + 1] + x2 * W1b[o * 3 + 2] + b1b[o]);
#pragma unroll
    for (int oo = 0; oo < 16; oo += 2) {
        int o = q * 16 + oo;
        float a0 = b2b[o], a1 = b2b[o + 1];
#pragma unroll
        for (int k = 0; k < 64; ++k) {
            a0 = fmaf(h[k], W2b[o * 64 + k], a0);
            a1 = fmaf(h[k], W2b[(o + 1) * 64 + k], a1);
        }
        __half2 hh = __floats2half2_rn(fmaxf(0.f, a0), fmaxf(0.f, a1));
        fbt[lane * 67 + q * 8 + (oo >> 1)] = *(float*)&hh;
    }
    float* vb = v + (size_t)b * 128 * NPTS + i;
#pragma unroll
    for (int oo = 0; oo < 8; ++oo) {
        int o = q * 8 + oo;
        vb[(size_t)o * NPTS] =
            fmaxf(0.f, x0 * Wc1[o * 3] + x1 * Wc1[o * 3 + 1] + x2 * Wc1[o * 3 + 2] + bc1[o]);
    }
    __syncthreads();

    uint* fau = (uint*)fa;
#pragma unroll
    for (int r = 0; r < 4; ++r) {
        int idx = r * 512 + tid;
        int pt = idx >> 5, j = idx & 31;
        fau[((size_t)(pbase + pt)) * 32 + j] = *(uint*)&fat[pt * 33 + j];
    }
    uint* fbu = (uint*)fb;
#pragma unroll
    for (int r = 0; r < 8; ++r) {
        int idx = r * 512 + tid;
        int pt = idx >> 6, j = idx & 63;
        fbu[((size_t)(pbase + pt)) * 64 + j] = *(uint*)&fbt[pt * 67 + j];
    }
}

// ---------------- K2a: ball query -> neighbor lists + counts ----------------
__global__ __launch_bounds__(1024) void k_ballot(
    const float* __restrict__ X, unsigned short* __restrict__ nbrg,
    int* __restrict__ cnt)
{
    __shared__ float4 xs4[NPTS];                  // 32KB {x,y,z,|y|^2}
    __shared__ unsigned short nbr[16][128];       // 4KB
    __shared__ int cts[16];
    int tid = threadIdx.x;
    int wid = tid >> 6, lane = tid & 63;
    int b = blockIdx.x & 7;
    int i0 = (blockIdx.x >> 3) * 16;
    int i = i0 + wid;

    const float* Xb = X + (size_t)b * NPTS * 3;
    for (int t = tid; t < NPTS; t += 1024) {
        float y0 = Xb[3 * t], y1 = Xb[3 * t + 1], y2 = Xb[3 * t + 2];
        float mm = fadd(fadd(fmul(y0, y0), fmul(y1, y1)), fmul(y2, y2));
        xs4[t] = make_float4(y0, y1, y2, mm);
    }
    __syncthreads();

    float4 cc = xs4[i];
    float n0 = cc.x, n1 = cc.y, n2 = cc.z, nn = cc.w;

    unsigned long long myword = 0;
    for (int w = 0; w < 32; ++w) {
        float4 y = xs4[(w << 6) | lane];
        float dot = fadd(fadd(fmul(n0, y.x), fmul(n1, y.y)), fmul(n2, y.z));
        float d   = fadd(fadd(fmul(-2.0f, dot), nn), y.w);
        unsigned long long bm = __ballot(!(d > R2C));
        if (lane == w) myword = bm;
    }

    int c = (lane < 32) ? __popcll(myword) : 0;
    int incl = c;
#pragma unroll
    for (int d = 1; d < 32; d <<= 1) {
        int t = __shfl_up(incl, d, 64);
        if (lane >= d) incl += t;
    }
    int pre = incl - c;
    if (lane < 32 && c && pre < 128) {
        unsigned long long word = myword;
        int r = pre;
        while (word && r < 128) {
            int pb = __builtin_ctzll(word);
            word &= word - 1;
            nbr[wid][r++] = (unsigned short)((lane << 6) | pb);
        }
    }
    // BUGFIX (R9): __shfl must be executed by ALL lanes. Inside `if(lane==0)`
    // the bpermute source (lane 31) is inactive -> returns 0 -> cnt==0 ->
    // cl=-1 -> LDS OOB -> wild gathers -> NaN. Hoist out of the predicate.
    int total = __shfl(incl, 31, 64);
    if (lane == 0) cts[wid] = total;
    __syncthreads();

    // coalesced writes: 1024 dwords (16 pts x 64) + 16 counts
    uint* ng = (uint*)(nbrg + ((size_t)b * NPTS + i0) * 128);
    ng[tid] = *(uint*)&nbr[tid >> 6][(tid & 63) * 2];
    if (tid < 16) cnt[(size_t)b * NPTS + i0 + tid] = cts[tid];
}

// ---------------- K2b: neighborhood max-pool (fp16 features) ----------------
// One wave per point; 8 waves (512 thr) -> VGPR cap 128 so the deep load
// batches actually stay in registers.
__global__ __launch_bounds__(512, 4) void k_pool(
    const __half* __restrict__ fa, const __half* __restrict__ fb,
    const unsigned short* __restrict__ nbrg, const int* __restrict__ cnt,
    float* __restrict__ v, float* __restrict__ out)
{
    __shared__ uint nbrl[8][64];                  // 2KB: 8 lists of 128 ushort
    __shared__ float g1t[64][9];                  // [ch][pt]
    __shared__ float g2t[128][9];                 // [ch][pt]
    int tid = threadIdx.x;
    int wid = __builtin_amdgcn_readfirstlane(tid >> 6);
    int lane = tid & 63;
    int b = blockIdx.x & 7;                       // batch-per-XCD L2 affinity
    int i0 = (blockIdx.x >> 3) * 8;
    int i = i0 + wid;

    nbrl[tid >> 6][tid & 63] = ((const uint*)(nbrg + ((size_t)b * NPTS + i0) * 128))[tid];
    int total = max(cnt[(size_t)b * NPTS + i], 1);   // wave-uniform; >=1 guard
    int c1 = min(total, 64), c2 = min(total, 128);
    __syncthreads();

    const unsigned short* list = (const unsigned short*)nbrl[wid];

    // ---- pool 1: first 64 -> max of fa. 8 rows/instr, 8 loads in flight ----
    {
        const uint4* fab = (const uint4*)(fa + (size_t)b * NPTS * 64);
        int g = lane >> 3, c8 = lane & 7;
        int cl = c1 - 1;
        uint4 r[8];
#pragma unroll
        for (int j = 0; j < 8; ++j) {
            int idx = j * 8 + g; idx = idx > cl ? cl : idx;
            r[j] = fab[(int)list[idx] * 8 + c8];
        }
        uint acc0 = 0, acc1 = 0, acc2 = 0, acc3 = 0;
#pragma unroll
        for (int j = 0; j < 8; ++j) {
            acc0 = hmax2u(acc0, r[j].x);
            acc1 = hmax2u(acc1, r[j].y);
            acc2 = hmax2u(acc2, r[j].z);
            acc3 = hmax2u(acc3, r[j].w);
        }
#pragma unroll
        for (int s = 8; s < 64; s <<= 1) {
            acc0 = hmax2u(acc0, (uint)__shfl_xor((int)acc0, s, 64));
            acc1 = hmax2u(acc1, (uint)__shfl_xor((int)acc1, s, 64));
            acc2 = hmax2u(acc2, (uint)__shfl_xor((int)acc2, s, 64));
            acc3 = hmax2u(acc3, (uint)__shfl_xor((int)acc3, s, 64));
        }
        if (g == 0) {
            uint a[4] = {acc0, acc1, acc2, acc3};
#pragma unroll
            for (int k = 0; k < 4; ++k) {
                g1t[8 * c8 + 2 * k][wid]     = lo_f(a[k]);
                g1t[8 * c8 + 2 * k + 1][wid] = hi_f(a[k]);
            }
        }
    }
    // ---- pool 2: first 128 -> max of fb. 4 rows/instr, 16 loads in flight ----
    {
        const uint4* fbb = (const uint4*)(fb + (size_t)b * NPTS * 128);
        int g = lane >> 4, c8 = lane & 15;
        int cl = c2 - 1;
        uint acc0 = 0, acc1 = 0, acc2 = 0, acc3 = 0;
#pragma unroll
        for (int jo = 0; jo < 32; jo += 16) {
            uint4 r[16];
#pragma unroll
            for (int jj = 0; jj < 16; ++jj) {
                int idx = (jo + jj) * 4 + g; idx = idx > cl ? cl : idx;
                r[jj] = fbb[(int)list[idx] * 16 + c8];
            }
#pragma unroll
            for (int jj = 0; jj < 16; ++jj) {
                acc0 = hmax2u(acc0, r[jj].x);
                acc1 = hmax2u(acc1, r[jj].y);
                acc2 = hmax2u(acc2, r[jj].z);
                acc3 = hmax2u(acc3, r[jj].w);
            }
        }
#pragma unroll
        for (int s = 16; s < 64; s <<= 1) {
            acc0 = hmax2u(acc0, (uint)__shfl_xor((int)acc0, s, 64));
            acc1 = hmax2u(acc1, (uint)__shfl_xor((int)acc1, s, 64));
            acc2 = hmax2u(acc2, (uint)__shfl_xor((int)acc2, s, 64));
            acc3 = hmax2u(acc3, (uint)__shfl_xor((int)acc3, s, 64));
        }
        if (g == 0) {
            uint a[4] = {acc0, acc1, acc2, acc3};
#pragma unroll
            for (int k = 0; k < 4; ++k) {
                g2t[8 * c8 + 2 * k][wid]     = lo_f(a[k]);
                g2t[8 * c8 + 2 * k + 1][wid] = hi_f(a[k]);
            }
        }
    }
    __syncthreads();

    // ---- cooperative stores (32B runs per 8-lane group) ----
    {
        int ch = tid >> 3, pt = tid & 7;
        v[((size_t)b * 128 + 64 + ch) * NPTS + i0 + pt] = g1t[ch][pt];
    }
#pragma unroll
    for (int r = 0; r < 2; ++r) {
        int idx = r * 512 + tid;
        int ch = idx >> 3, pt = idx & 7;
        out[((size_t)b * 384 + 256 + ch) * NPTS + i0 + pt] = g2t[ch][pt];
    }
}

// ---------------- K3: 256x128 pointwise conv (unchanged from R8) ----------------
__global__ __launch_bounds__(256) void k_conv2(
    const float* __restrict__ v, const float* __restrict__ Wc2,
    const float* __restrict__ bc2, float* __restrict__ out)
{
    __shared__ float vs[128 * 32];
    __shared__ float ws[256 * 33];
    int b = blockIdx.x & 7;
    int nt = (blockIdx.x >> 3) << 5;
    int t = threadIdx.x;
    int n_t = t & 3, o_t = t >> 2;

    const float* vb = v + (size_t)b * 128 * NPTS + nt;
#pragma unroll
    for (int r = 0; r < 4; ++r) {
        int j = r * 256 + t; int k = j >> 3, n4 = j & 7;
        *(float4*)&vs[k * 32 + n4 * 4] = *(const float4*)(vb + (size_t)k * NPTS + n4 * 4);
    }

    float acc[4][8];
#pragma unroll
    for (int r = 0; r < 4; ++r) {
        float bb = bc2[o_t * 4 + r];
#pragma unroll
        for (int n = 0; n < 8; ++n) acc[r][n] = bb;
    }

    for (int kc = 0; kc < 128; kc += 32) {
        __syncthreads();
#pragma unroll
        for (int r = 0; r < 8; ++r) {
            int j = r * 256 + t; int o = j >> 3, c = j & 7;
            float4 wv = *(const float4*)(Wc2 + (size_t)o * 128 + kc + c * 4);
            ws[o * 33 + c * 4 + 0] = wv.x;
            ws[o * 33 + c * 4 + 1] = wv.y;
            ws[o * 33 + c * 4 + 2] = wv.z;
            ws[o * 33 + c * 4 + 3] = wv.w;
        }
        __syncthreads();
#pragma unroll 4
        for (int kk = 0; kk < 32; ++kk) {
            float4 va = *(float4*)&vs[(kc + kk) * 32 + n_t * 8];
            float4 vb4 = *(float4*)&vs[(kc + kk) * 32 + n_t * 8 + 4];
            float vv[8] = {va.x, va.y, va.z, va.w, vb4.x, vb4.y, vb4.z, vb4.w};
            float ww[4];
#pragma unroll
            for (int r = 0; r < 4; ++r) ww[r] = ws[(o_t * 4 + r) * 33 + kk];
#pragma unroll
            for (int r = 0; r < 4; ++r)
#pragma unroll
                for (int n = 0; n < 8; ++n)
                    acc[r][n] = fmaf(ww[r], vv[n], acc[r][n]);
        }
    }

    float* ob = out + ((size_t)b * 384 + o_t * 4) * NPTS + nt + n_t * 8;
#pragma unroll
    for (int r = 0; r < 4; ++r) {
        float4 s0, s1;
        s0.x = fmaxf(0.f, acc[r][0]); s0.y = fmaxf(0.f, acc[r][1]);
        s0.z = fmaxf(0.f, acc[r][2]); s0.w = fmaxf(0.f, acc[r][3]);
        s1.x = fmaxf(0.f, acc[r][4]); s1.y = fmaxf(0.f, acc[r][5]);
        s1.z = fmaxf(0.f, acc[r][6]); s1.w = fmaxf(0.f, acc[r][7]);
        *(float4*)(ob + (size_t)r * NPTS) = s0;
        *(float4*)(ob + (size_t)r * NPTS + 4) = s1;
    }
}

extern "C" void kernel_launch(void* const* d_in, const int* in_sizes, int n_in,
                              void* d_out, int out_size, void* d_ws, size_t ws_size,
                              hipStream_t stream) {
    const float* X   = (const float*)d_in[0];
    const float* W1a = (const float*)d_in[1];
    const float* b1a = (const float*)d_in[2];
    const float* W2a = (const float*)d_in[3];
    const float* b2a = (const float*)d_in[4];
    const float* W1b = (const float*)d_in[5];
    const float* b1b = (const float*)d_in[6];
    const float* W2b = (const float*)d_in[7];
    const float* b2b = (const float*)d_in[8];
    const float* Wc1 = (const float*)d_in[9];
    const float* bc1 = (const float*)d_in[10];
    const float* Wc2 = (const float*)d_in[11];
    const float* bc2 = (const float*)d_in[12];
    float* out = (float*)d_out;

    // workspace: fa 2MB | fb 4MB | v 8MB | nbrg 4MB | cnt 64KB  (~18.1MB)
    __half* fa = (__half*)d_ws;
    __half* fb = fa + (size_t)NB * NPTS * 64;
    float*  v  = (float*)(fb + (size_t)NB * NPTS * 128);
    unsigned short* nbrg = (unsigned short*)(v + (size_t)NB * 128 * NPTS);
    int* cnt = (int*)(nbrg + (size_t)NB * NPTS * 128);

    k_features<<<NB * NPTS / 64, 512, 0, stream>>>(X, W1a, b1a, W2a, b2a,
                                                   W1b, b1b, W2b, b2b, Wc1, bc1,
                                                   fa, fb, v);
    k_ballot<<<NB * NPTS / 16, 1024, 0, stream>>>(X, nbrg, cnt);
    k_pool<<<NB * NPTS / 8, 512, 0, stream>>>(fa, fb, nbrg, cnt, v, out);
    k_conv2<<<NB * (NPTS / 32), 256, 0, stream>>>(v, Wc2, bc2, out);
}

// Round 13
// 164.696 us; speedup vs baseline: 1.0848x; 1.0848x over previous
//
#include <hip/hip_runtime.h>
#include <hip/hip_fp16.h>
#include <cstdint>

#define NPTS 2048
#define NB 8
// float32 of (0.45*0.45 computed in float64) -- matches jnp/np scalar cast.
// NOTE: 0.45f*0.45f is 1 ulp LOWER; do not use it.
#define R2C 0.2025f

__device__ __forceinline__ float fmul(float a, float b) { return __fmul_rn(a, b); }
__device__ __forceinline__ float fadd(float a, float b) { return __fadd_rn(a, b); }

// packed fp16 max (header lacks __hmax2 on gfx950; ISA has v_pk_max_f16)
__device__ __forceinline__ uint hmax2u(uint a, uint b) {
    uint r;
    asm volatile("v_pk_max_f16 %0, %1, %2" : "=v"(r) : "v"(a), "v"(b));
    return r;
}
__device__ __forceinline__ float lo_f(uint u) {
    __half h = __ushort_as_half((unsigned short)(u & 0xffff));
    return __half2float(h);
}
__device__ __forceinline__ float hi_f(uint u) {
    __half h = __ushort_as_half((unsigned short)(u >> 16));
    return __half2float(h);
}

// ---------------- K1: per-point features (unchanged from R10) ----------------
__global__ __launch_bounds__(512, 4) void k_features(
    const float* __restrict__ X,
    const float* __restrict__ W1a, const float* __restrict__ b1a,
    const float* __restrict__ W2a, const float* __restrict__ b2a,
    const float* __restrict__ W1b, const float* __restrict__ b1b,
    const float* __restrict__ W2b, const float* __restrict__ b2b,
    const float* __restrict__ Wc1, const float* __restrict__ bc1,
    __half* __restrict__ fa, __half* __restrict__ fb, float* __restrict__ v)
{
    __shared__ float fat[64 * 33];
    __shared__ float fbt[64 * 67];
    int tid = threadIdx.x;
    int q = __builtin_amdgcn_readfirstlane(tid >> 6);   // wave 0..7 (SGPR)
    int lane = tid & 63;
    int pbase = blockIdx.x * 64;
    int p = pbase + lane;
    int b = p >> 11, i = p & 2047;

    float x0 = X[p * 3 + 0], x1 = X[p * 3 + 1], x2 = X[p * 3 + 2];

    float h[64];
#pragma unroll
    for (int o = 0; o < 32; ++o)
        h[o] = fmaxf(0.f, x0 * W1a[o * 3] + x1 * W1a[o * 3 + 1] + x2 * W1a[o * 3 + 2] + b1a[o]);
#pragma unroll
    for (int oo = 0; oo < 8; oo += 2) {
        int o = q * 8 + oo;
        float a0 = b2a[o], a1 = b2a[o + 1];
#pragma unroll
        for (int k = 0; k < 32; ++k) {
            a0 = fmaf(h[k], W2a[o * 32 + k], a0);
            a1 = fmaf(h[k], W2a[(o + 1) * 32 + k], a1);
        }
        __half2 hh = __floats2half2_rn(fmaxf(0.f, a0), fmaxf(0.f, a1));
        fat[lane * 33 + q * 4 + (oo >> 1)] = *(float*)&hh;
    }
#pragma unroll
    for (int o = 0; o < 64; ++o)
        h[o] = fmaxf(0.f, x0 * W1b[o * 3] + x1 * W1b[o * 3 + 1] + x2 * W1b[o * 3 + 2] + b1b[o]);
#pragma unroll
    for (int oo = 0; oo < 16; oo += 2) {
        int o = q * 16 + oo;
        float a0 = b2b[o], a1 = b2b[o + 1];
#pragma unroll
        for (int k = 0; k < 64; ++k) {
            a0 = fmaf(h[k], W2b[o * 64 + k], a0);
            a1 = fmaf(h[k], W2b[(o + 1) * 64 + k], a1);
        }
        __half2 hh = __floats2half2_rn(fmaxf(0.f, a0), fmaxf(0.f, a1));
        fbt[lane * 67 + q * 8 + (oo >> 1)] = *(float*)&hh;
    }
    float* vb = v + (size_t)b * 128 * NPTS + i;
#pragma unroll
    for (int oo = 0; oo < 8; ++oo) {
        int o = q * 8 + oo;
        vb[(size_t)o * NPTS] =
            fmaxf(0.f, x0 * Wc1[o * 3] + x1 * Wc1[o * 3 + 1] + x2 * Wc1[o * 3 + 2] + bc1[o]);
    }
    __syncthreads();

    uint* fau = (uint*)fa;
#pragma unroll
    for (int r = 0; r < 4; ++r) {
        int idx = r * 512 + tid;
        int pt = idx >> 5, j = idx & 31;
        fau[((size_t)(pbase + pt)) * 32 + j] = *(uint*)&fat[pt * 33 + j];
    }
    uint* fbu = (uint*)fb;
#pragma unroll
    for (int r = 0; r < 8; ++r) {
        int idx = r * 512 + tid;
        int pt = idx >> 6, j = idx & 63;
        fbu[((size_t)(pbase + pt)) * 64 + j] = *(uint*)&fbt[pt * 67 + j];
    }
}

// ---------------- K2: fused ball query + max-pool ----------------
// 512 threads = 8 waves, one point per wave. Ballot -> LDS list -> pool,
// all wave-local (no global nbr round-trip, no extra barrier: each wave
// writes and reads only nbr[wid]). launch_bounds(512,4) keeps VGPR cap at
// 128 so the 8/16-deep gather batches stay in registers.
__global__ __launch_bounds__(512, 4) void k_query(
    const float* __restrict__ X, const __half* __restrict__ fa,
    const __half* __restrict__ fb, float* __restrict__ v, float* __restrict__ out)
{
    __shared__ float4 xs4[NPTS];                  // 32KB {x,y,z,|y|^2}
    __shared__ unsigned short nbr[8][128];        // 2KB
    __shared__ float g1t[64][9];                  // [ch][pt]
    __shared__ float g2t[128][9];                 // [ch][pt]
    int tid = threadIdx.x;
    int wid = __builtin_amdgcn_readfirstlane(tid >> 6);
    int lane = tid & 63;
    int b = blockIdx.x & 7;                       // batch-per-XCD L2 affinity
    int i0 = (blockIdx.x >> 3) * 8;
    int i = i0 + wid;                             // this wave's point

    const float* Xb = X + (size_t)b * NPTS * 3;
    for (int t = tid; t < NPTS; t += 512) {
        float y0 = Xb[3 * t], y1 = Xb[3 * t + 1], y2 = Xb[3 * t + 2];
        float mm = fadd(fadd(fmul(y0, y0), fmul(y1, y1)), fmul(y2, y2));
        xs4[t] = make_float4(y0, y1, y2, mm);
    }
    __syncthreads();

    float4 cc = xs4[i];
    float n0 = cc.x, n1 = cc.y, n2 = cc.z, nn = cc.w;

    // 32 ballot words; lane w keeps word w (exact numpy arithmetic, no FMA)
    unsigned long long myword = 0;
    for (int w = 0; w < 32; ++w) {
        float4 y = xs4[(w << 6) | lane];
        float dot = fadd(fadd(fmul(n0, y.x), fmul(n1, y.y)), fmul(n2, y.z));
        float d   = fadd(fadd(fmul(-2.0f, dot), nn), y.w);
        unsigned long long bm = __ballot(!(d > R2C));
        if (lane == w) myword = bm;
    }

    // parallel decode: prefix-sum of per-word popcounts -> rank base
    int c = (lane < 32) ? __popcll(myword) : 0;
    int incl = c;
#pragma unroll
    for (int d = 1; d < 32; d <<= 1) {
        int t = __shfl_up(incl, d, 64);
        if (lane >= d) incl += t;
    }
    int pre = incl - c;
    if (lane < 32 && c && pre < 128) {
        unsigned long long word = myword;
        int r = pre;
        while (word && r < 128) {
            int pb = __builtin_ctzll(word);
            word &= word - 1;
            nbr[wid][r++] = (unsigned short)((lane << 6) | pb);
        }
    }
    // __shfl executed by ALL lanes (R9 lesson: inactive-source bpermute = 0)
    int total = __shfl(incl, 31, 64);             // >= 1: self-distance == 0
    int c1 = min(total, 64), c2 = min(total, 128);

    const unsigned short* list = nbr[wid];        // same-wave LDS, no barrier

    // ---- pool 1: first 64 -> max of fa. 8 rows/instr, 8 loads in flight ----
    {
        const uint4* fab = (const uint4*)(fa + (size_t)b * NPTS * 64);
        int g = lane >> 3, c8 = lane & 7;
        int cl = c1 - 1;
        uint4 r[8];
#pragma unroll
        for (int j = 0; j < 8; ++j) {
            int idx = j * 8 + g; idx = idx > cl ? cl : idx;
            r[j] = fab[(int)list[idx] * 8 + c8];
        }
        uint acc0 = 0, acc1 = 0, acc2 = 0, acc3 = 0;
#pragma unroll
        for (int j = 0; j < 8; ++j) {
            acc0 = hmax2u(acc0, r[j].x);
            acc1 = hmax2u(acc1, r[j].y);
            acc2 = hmax2u(acc2, r[j].z);
            acc3 = hmax2u(acc3, r[j].w);
        }
#pragma unroll
        for (int s = 8; s < 64; s <<= 1) {
            acc0 = hmax2u(acc0, (uint)__shfl_xor((int)acc0, s, 64));
            acc1 = hmax2u(acc1, (uint)__shfl_xor((int)acc1, s, 64));
            acc2 = hmax2u(acc2, (uint)__shfl_xor((int)acc2, s, 64));
            acc3 = hmax2u(acc3, (uint)__shfl_xor((int)acc3, s, 64));
        }
        if (g == 0) {
            uint a[4] = {acc0, acc1, acc2, acc3};
#pragma unroll
            for (int k = 0; k < 4; ++k) {
                g1t[8 * c8 + 2 * k][wid]     = lo_f(a[k]);
                g1t[8 * c8 + 2 * k + 1][wid] = hi_f(a[k]);
            }
        }
    }
    // ---- pool 2: first 128 -> max of fb. 4 rows/instr, 16 loads in flight ----
    {
        const uint4* fbb = (const uint4*)(fb + (size_t)b * NPTS * 128);
        int g = lane >> 4, c8 = lane & 15;
        int cl = c2 - 1;
        uint acc0 = 0, acc1 = 0, acc2 = 0, acc3 = 0;
#pragma unroll
        for (int jo = 0; jo < 32; jo += 16) {
            uint4 r[16];
#pragma unroll
            for (int jj = 0; jj < 16; ++jj) {
                int idx = (jo + jj) * 4 + g; idx = idx > cl ? cl : idx;
                r[jj] = fbb[(int)list[idx] * 16 + c8];
            }
#pragma unroll
            for (int jj = 0; jj < 16; ++jj) {
                acc0 = hmax2u(acc0, r[jj].x);
                acc1 = hmax2u(acc1, r[jj].y);
                acc2 = hmax2u(acc2, r[jj].z);
                acc3 = hmax2u(acc3, r[jj].w);
            }
        }
#pragma unroll
        for (int s = 16; s < 64; s <<= 1) {
            acc0 = hmax2u(acc0, (uint)__shfl_xor((int)acc0, s, 64));
            acc1 = hmax2u(acc1, (uint)__shfl_xor((int)acc1, s, 64));
            acc2 = hmax2u(acc2, (uint)__shfl_xor((int)acc2, s, 64));
            acc3 = hmax2u(acc3, (uint)__shfl_xor((int)acc3, s, 64));
        }
        if (g == 0) {
            uint a[4] = {acc0, acc1, acc2, acc3};
#pragma unroll
            for (int k = 0; k < 4; ++k) {
                g2t[8 * c8 + 2 * k][wid]     = lo_f(a[k]);
                g2t[8 * c8 + 2 * k + 1][wid] = hi_f(a[k]);
            }
        }
    }
    __syncthreads();

    // ---- cooperative stores (32B runs per 8-lane group) ----
    {
        int ch = tid >> 3, pt = tid & 7;
        v[((size_t)b * 128 + 64 + ch) * NPTS + i0 + pt] = g1t[ch][pt];
    }
#pragma unroll
    for (int r = 0; r < 2; ++r) {
        int idx = r * 512 + tid;
        int ch = idx >> 3, pt = idx & 7;
        out[((size_t)b * 384 + 256 + ch) * NPTS + i0 + pt] = g2t[ch][pt];
    }
}

// ---------------- K3: 256x128 pointwise conv (unchanged from R10) ----------------
__global__ __launch_bounds__(256) void k_conv2(
    const float* __restrict__ v, const float* __restrict__ Wc2,
    const float* __restrict__ bc2, float* __restrict__ out)
{
    __shared__ float vs[128 * 32];
    __shared__ float ws[256 * 33];
    int b = blockIdx.x & 7;
    int nt = (blockIdx.x >> 3) << 5;
    int t = threadIdx.x;
    int n_t = t & 3, o_t = t >> 2;

    const float* vb = v + (size_t)b * 128 * NPTS + nt;
#pragma unroll
    for (int r = 0; r < 4; ++r) {
        int j = r * 256 + t; int k = j >> 3, n4 = j & 7;
        *(float4*)&vs[k * 32 + n4 * 4] = *(const float4*)(vb + (size_t)k * NPTS + n4 * 4);
    }

    float acc[4][8];
#pragma unroll
    for (int r = 0; r < 4; ++r) {
        float bb = bc2[o_t * 4 + r];
#pragma unroll
        for (int n = 0; n < 8; ++n) acc[r][n] = bb;
    }

    for (int kc = 0; kc < 128; kc += 32) {
        __syncthreads();
#pragma unroll
        for (int r = 0; r < 8; ++r) {
            int j = r * 256 + t; int o = j >> 3, c = j & 7;
            float4 wv = *(const float4*)(Wc2 + (size_t)o * 128 + kc + c * 4);
            ws[o * 33 + c * 4 + 0] = wv.x;
            ws[o * 33 + c * 4 + 1] = wv.y;
            ws[o * 33 + c * 4 + 2] = wv.z;
            ws[o * 33 + c * 4 + 3] = wv.w;
        }
        __syncthreads();
#pragma unroll 4
        for (int kk = 0; kk < 32; ++kk) {
            float4 va = *(float4*)&vs[(kc + kk) * 32 + n_t * 8];
            float4 vb4 = *(float4*)&vs[(kc + kk) * 32 + n_t * 8 + 4];
            float vv[8] = {va.x, va.y, va.z, va.w, vb4.x, vb4.y, vb4.z, vb4.w};
            float ww[4];
#pragma unroll
            for (int r = 0; r < 4; ++r) ww[r] = ws[(o_t * 4 + r) * 33 + kk];
#pragma unroll
            for (int r = 0; r < 4; ++r)
#pragma unroll
                for (int n = 0; n < 8; ++n)
                    acc[r][n] = fmaf(ww[r], vv[n], acc[r][n]);
        }
    }

    float* ob = out + ((size_t)b * 384 + o_t * 4) * NPTS + nt + n_t * 8;
#pragma unroll
    for (int r = 0; r < 4; ++r) {
        float4 s0, s1;
        s0.x = fmaxf(0.f, acc[r][0]); s0.y = fmaxf(0.f, acc[r][1]);
        s0.z = fmaxf(0.f, acc[r][2]); s0.w = fmaxf(0.f, acc[r][3]);
        s1.x = fmaxf(0.f, acc[r][4]); s1.y = fmaxf(0.f, acc[r][5]);
        s1.z = fmaxf(0.f, acc[r][6]); s1.w = fmaxf(0.f, acc[r][7]);
        *(float4*)(ob + (size_t)r * NPTS) = s0;
        *(float4*)(ob + (size_t)r * NPTS + 4) = s1;
    }
}

extern "C" void kernel_launch(void* const* d_in, const int* in_sizes, int n_in,
                              void* d_out, int out_size, void* d_ws, size_t ws_size,
                              hipStream_t stream) {
    const float* X   = (const float*)d_in[0];
    const float* W1a = (const float*)d_in[1];
    const float* b1a = (const float*)d_in[2];
    const float* W2a = (const float*)d_in[3];
    const float* b2a = (const float*)d_in[4];
    const float* W1b = (const float*)d_in[5];
    const float* b1b = (const float*)d_in[6];
    const float* W2b = (const float*)d_in[7];
    const float* b2b = (const float*)d_in[8];
    const float* Wc1 = (const float*)d_in[9];
    const float* bc1 = (const float*)d_in[10];
    const float* Wc2 = (const float*)d_in[11];
    const float* bc2 = (const float*)d_in[12];
    float* out = (float*)d_out;

    // workspace: fa 2MB | fb 4MB | v 8MB  (~14MB)
    __half* fa = (__half*)d_ws;
    __half* fb = fa + (size_t)NB * NPTS * 64;
    float*  v  = (float*)(fb + (size_t)NB * NPTS * 128);

    k_features<<<NB * NPTS / 64, 512, 0, stream>>>(X, W1a, b1a, W2a, b2a,
                                                   W1b, b1b, W2b, b2b, Wc1, bc1,
                                                   fa, fb, v);
    k_query<<<NB * NPTS / 8, 512, 0, stream>>>(X, fa, fb, v, out);
    k_conv2<<<NB * (NPTS / 32), 256, 0, stream>>>(v, Wc2, bc2, out);
}